// Round 3
// baseline (462.666 us; speedup 1.0000x reference)
//
#include <hip/hip_runtime.h>

#define N_ 16
#define T_ 8
#define L_ 197
#define H_ 12
#define D_ 64
#define Q_ 196
#define C_ 768
#define KP 224          // padded K/pos dimension (7 x 32)
#define ENT 1792        // 8 dchunks * 224 pos, 16B entries per (nt,h) plane

typedef unsigned short ushort_t;
typedef __bf16 bf16x8 __attribute__((ext_vector_type(8)));
typedef float floatx4 __attribute__((ext_vector_type(4)));

static __device__ inline ushort_t f2bf(float x) {
  unsigned int u = __float_as_uint(x);
  u += 0x7fffu + ((u >> 16) & 1u);       // RNE
  return (ushort_t)(u >> 16);
}
static __device__ inline unsigned int pack2(float a, float b) {
  return (unsigned int)f2bf(a) | ((unsigned int)f2bf(b) << 16);
}

// ------------- Pass 0: q,k fp32 -> bf16, transposed [nt][h][dc 8][pos 224] --
// Each 16B entry = 8 bf16 = d-chunk dc of row l=1+pos. pos>=196 zeroed.
// q scaled by 0.125 (exact in bf16).
__global__ __launch_bounds__(256) void convert_kernel(
    const float* __restrict__ q, const float* __restrict__ k,
    uint4* __restrict__ qb, uint4* __restrict__ kb) {
  const int nt = blockIdx.x;       // 0..127
  const int h  = blockIdx.y;       // 0..11
  const int tid = threadIdx.x;
  const size_t pbase = ((size_t)nt * H_ + h) * ENT;
  #pragma unroll
  for (int r = 0; r < 7; r++) {
    int e = tid + 256 * r;                // < 1792
    int dc = e / KP, pos = e - dc * KP;
    uint4 oq = {0u, 0u, 0u, 0u}, ok = {0u, 0u, 0u, 0u};
    if (pos < Q_) {
      const size_t src = (((size_t)nt * L_ + 1 + pos) * H_ + h) * D_ + dc * 8;
      float4 a = *(const float4*)(q + src);
      float4 b = *(const float4*)(q + src + 4);
      oq.x = pack2(a.x * 0.125f, a.y * 0.125f);
      oq.y = pack2(a.z * 0.125f, a.w * 0.125f);
      oq.z = pack2(b.x * 0.125f, b.y * 0.125f);
      oq.w = pack2(b.z * 0.125f, b.w * 0.125f);
      float4 c = *(const float4*)(k + src);
      float4 d = *(const float4*)(k + src + 4);
      ok.x = pack2(c.x, c.y);
      ok.y = pack2(c.z, c.w);
      ok.z = pack2(d.x, d.y);
      ok.w = pack2(d.z, d.w);
    }
    qb[pbase + e] = oq;
    kb[pbase + e] = ok;
  }
}

// ------------- Stage 1: A[qi][nt][k] = mean_h softmax_k(QK^T/8), bf16 ------
// grid (4 m-blocks, 112 nt, 2 halves), block 256 = 4 waves.
// K plane (28KB) staged in LDS, next head register-prefetched; Q frags direct.
__global__ __launch_bounds__(256) void attn_kernel(
    const uint4* __restrict__ qb, const uint4* __restrict__ kb,
    ushort_t* __restrict__ A1, ushort_t* __restrict__ A2) {
  const int b    = blockIdx.x;       // 0..3
  const int nt   = blockIdx.y;       // 0..111
  const int half = blockIdx.z;
  const int n  = nt / 7, tp = nt % 7;
  const int tq = (half == 0) ? tp + 1 : tp;
  const int tk = (half == 0) ? tp     : tp + 1;
  const int ntq = n * T_ + tq;       // output (n,t) slot
  const int ntk = n * T_ + tk;

  const uint4* qpl = qb + (size_t)ntq * H_ * ENT;
  const uint4* kpl = kb + (size_t)ntk * H_ * ENT;
  ushort_t* Ah = (half == 0) ? A1 : A2;

  __shared__ uint4 ks[ENT];          // 28 KB, [dc 8][ki 224]

  const int tid  = threadIdx.x;
  const int lane = tid & 63;
  const int wv   = tid >> 6;
  const int quad = lane >> 4;
  const int l15  = lane & 15;
  const int qi_b = 64 * b + 16 * wv;

  float accA[13][4];
  #pragma unroll
  for (int t = 0; t < 13; t++)
    #pragma unroll
    for (int r = 0; r < 4; r++) accA[t][r] = 0.f;

  // preload head 0 into regs
  uint4 kreg[7];
  #pragma unroll
  for (int r = 0; r < 7; r++) kreg[r] = kpl[tid + 256 * r];

  for (int h = 0; h < H_; h++) {
    __syncthreads();                 // all waves done reading ks (prev head)
    #pragma unroll
    for (int r = 0; r < 7; r++) ks[tid + 256 * r] = kreg[r];
    // prefetch next head (latency hidden under this head's compute)
    if (h + 1 < H_) {
      #pragma unroll
      for (int r = 0; r < 7; r++) kreg[r] = kpl[(size_t)(h + 1) * ENT + tid + 256 * r];
    }
    // Q fragments direct from global (coalesced 16B/lane)
    bf16x8 qf[2];
    #pragma unroll
    for (int kk = 0; kk < 2; kk++)
      qf[kk] = *(const bf16x8*)&qpl[(size_t)h * ENT + (quad + 4 * kk) * KP + qi_b + l15];
    __syncthreads();                 // ks ready

    floatx4 S[13];
    #pragma unroll
    for (int t = 0; t < 13; t++) S[t] = (floatx4){0.f, 0.f, 0.f, 0.f};
    #pragma unroll
    for (int kk = 0; kk < 2; kk++)
      #pragma unroll
      for (int t = 0; t < 13; t++) {
        bf16x8 bbv = *(const bf16x8*)&ks[(quad + 4 * kk) * KP + 16 * t + l15];
        S[t] = __builtin_amdgcn_mfma_f32_16x16x32_bf16(qf[kk], bbv, S[t], 0, 0, 0);
      }

    // softmax over k (no max pass: logits ~ N(0,1)), accumulate P/rowsum
    #pragma unroll
    for (int r = 0; r < 4; r++) {
      float s = 0.f;
      #pragma unroll
      for (int t = 0; t < 13; t++) {
        float e_ = (t == 12 && l15 >= 4) ? 0.f : __expf(S[t][r]);
        S[t][r] = e_;
        s += e_;
      }
      #pragma unroll
      for (int off = 1; off < 16; off <<= 1) s += __shfl_xor(s, off);
      float inv = 1.f / s;
      #pragma unroll
      for (int t = 0; t < 13; t++) accA[t][r] += S[t][r] * inv;
    }
  }

  // store A * (1/12) as bf16; layout [qi][ntm][KP]
  const float s12 = 1.f / 12.f;
  #pragma unroll
  for (int t = 0; t < 13; t++)
    #pragma unroll
    for (int r = 0; r < 4; r++) {
      int qi = qi_b + 4 * quad + r;
      if (qi < Q_)
        Ah[((size_t)qi * (N_ * T_) + ntq) * KP + 16 * t + l15] = f2bf(accA[t][r] * s12);
    }
}

// ------------- Stage 2: out[nt,qi,c] = sum_half A_h[qi] @ gather(W_h) ------
// grid (6 c-tiles of 128, 196 qi), block 256 = 4 waves; wave -> 32 c.
__global__ __launch_bounds__(256) void mix_kernel(
    const ushort_t* __restrict__ A1, const ushort_t* __restrict__ A2,
    const float* __restrict__ w1, const float* __restrict__ w2,
    const int* __restrict__ idx, float* __restrict__ out) {
  const int ct = blockIdx.x;   // 0..5
  const int qi = blockIdx.y;   // 0..195
  const int tid  = threadIdx.x;
  const int lane = tid & 63;
  const int wv   = tid >> 6;
  const int quad = lane >> 4;
  const int l15  = lane & 15;

  __shared__ ushort_t As[128][40];   // [m][k 32], pad 40 (80B rows)
  __shared__ ushort_t Ws[128][40];   // [c][k 32] (B-frag layout)

  floatx4 acc[8][2];
  #pragma unroll
  for (int mt = 0; mt < 8; mt++)
    #pragma unroll
    for (int u = 0; u < 2; u++) acc[mt][u] = (floatx4){0.f, 0.f, 0.f, 0.f};

  const int* idxq = idx + qi * Q_;

  #pragma unroll
  for (int half = 0; half < 2; half++) {
    const ushort_t* Ah = half ? A2 : A1;
    const float* w = half ? w2 : w1;
    for (int kc = 0; kc < 7; kc++) {
      const int k0 = 32 * kc;
      __syncthreads();
      // stage A: 128 rows x 4 16B-chunks = 512 -> 2/thread
      #pragma unroll
      for (int r = 0; r < 2; r++) {
        int e = tid + 256 * r;
        int row = e >> 2, ch = e & 3;
        *(uint4*)&As[row][ch * 8] =
            *(const uint4*)(Ah + ((size_t)qi * (N_ * T_) + row) * KP + k0 + ch * 8);
      }
      // gather W (32 k x 128 c fp32), pack k-pairs -> b32 LDS writes.
      // lane mapping: kk2 = lane&15 (k-pair), cc = e>>4 (c-chunk of 4) ->
      // LDS write banks 2-way (free); gathers are 16B granules from L2-hot W.
      #pragma unroll
      for (int r = 0; r < 2; r++) {
        int e = tid + 256 * r;
        int cc = e >> 4, kk2 = e & 15;
        int gk0 = k0 + 2 * kk2, gk1 = gk0 + 1;
        float4 v0 = make_float4(0.f, 0.f, 0.f, 0.f), v1 = v0;
        if (gk0 < Q_) v0 = *(const float4*)(w + (size_t)idxq[gk0] * C_ + ct * 128 + cc * 4);
        if (gk1 < Q_) v1 = *(const float4*)(w + (size_t)idxq[gk1] * C_ + ct * 128 + cc * 4);
        *(unsigned int*)&Ws[cc * 4 + 0][2 * kk2] = pack2(v0.x, v1.x);
        *(unsigned int*)&Ws[cc * 4 + 1][2 * kk2] = pack2(v0.y, v1.y);
        *(unsigned int*)&Ws[cc * 4 + 2][2 * kk2] = pack2(v0.z, v1.z);
        *(unsigned int*)&Ws[cc * 4 + 3][2 * kk2] = pack2(v0.w, v1.w);
      }
      __syncthreads();
      bf16x8 bfv[2];
      #pragma unroll
      for (int u = 0; u < 2; u++)
        bfv[u] = *(const bf16x8*)&Ws[32 * wv + 16 * u + l15][8 * quad];
      #pragma unroll
      for (int mt = 0; mt < 8; mt++) {
        bf16x8 a = *(const bf16x8*)&As[16 * mt + l15][8 * quad];
        acc[mt][0] = __builtin_amdgcn_mfma_f32_16x16x32_bf16(a, bfv[0], acc[mt][0], 0, 0, 0);
        acc[mt][1] = __builtin_amdgcn_mfma_f32_16x16x32_bf16(a, bfv[1], acc[mt][1], 0, 0, 0);
      }
    }
  }

  #pragma unroll
  for (int u = 0; u < 2; u++) {
    const int c = ct * 128 + 32 * wv + 16 * u + l15;
    #pragma unroll
    for (int mt = 0; mt < 8; mt++)
      #pragma unroll
      for (int r = 0; r < 4; r++) {
        int m = 16 * mt + 4 * quad + r;
        out[((size_t)m * L_ + 1 + qi) * C_ + c] = acc[mt][u][r];
      }
  }
  if (qi == 0) {
    #pragma unroll
    for (int u = 0; u < 2; u++) {
      const int c = ct * 128 + 32 * wv + 16 * u + l15;
      #pragma unroll
      for (int mt = 0; mt < 8; mt++)
        #pragma unroll
        for (int r = 0; r < 4; r++) {
          int m = 16 * mt + 4 * quad + r;
          out[(size_t)m * L_ * C_ + c] = 0.f;
        }
    }
  }
}

extern "C" void kernel_launch(void* const* d_in, const int* in_sizes, int n_in,
                              void* d_out, int out_size, void* d_ws, size_t ws_size,
                              hipStream_t stream) {
  const float* q  = (const float*)d_in[0];
  const float* k  = (const float*)d_in[1];
  const float* w1 = (const float*)d_in[2];
  const float* w2 = (const float*)d_in[3];
  const int* idx  = (const int*)d_in[4];
  float* out = (float*)d_out;

  const size_t plane_tot = (size_t)(N_ * T_) * H_ * ENT;   // uint4 entries
  uint4* qb = (uint4*)d_ws;
  uint4* kb = qb + plane_tot;
  ushort_t* A1 = (ushort_t*)(kb + plane_tot);
  size_t Aelems = (size_t)Q_ * (N_ * T_) * KP;
  ushort_t* A2 = A1 + Aelems;

  // zero A buffers: covers k-pad cols 208..223 and empty t-slots
  hipMemsetAsync(A1, 0, Aelems * 2 * sizeof(ushort_t), stream);

  convert_kernel<<<dim3(N_ * T_, H_), 256, 0, stream>>>(q, k, qb, kb);
  attn_kernel<<<dim3(4, 112, 2), 256, 0, stream>>>(qb, kb, A1, A2);
  mix_kernel<<<dim3(6, Q_), 256, 0, stream>>>(A1, A2, w1, w2, idx, out);
}